// Round 1
// baseline (87.985 us; speedup 1.0000x reference)
//
#include <hip/hip_runtime.h>
#include <hip/hip_bf16.h>

// SoftPointRenderer: B=4, K=8, N=256 points -> (B,1,96,96) image.
// Separable Gaussian splat: img[b,h,w] = sum_p ey[p,h]*ex[p,w]; out = 1-exp(-img).

#define HDIM 96
#define WDIM 96
#define PTS_PER_BATCH 2048   // K*N = 8*256
#define P_CHUNK 64           // points per block
#define CHUNKS 32            // 2048 / 64
#define BATCHES 4

__global__ __launch_bounds__(256)
void splat_kernel(const float* __restrict__ pts, float* __restrict__ img) {
    __shared__ float sex[P_CHUNK][WDIM];   // 24 KB
    __shared__ float sey[P_CHUNK][HDIM];   // 24 KB
    __shared__ float su[P_CHUNK], sv[P_CHUNK], sval[P_CHUNK];

    const int b = blockIdx.x >> 5;          // / CHUNKS
    const int c = blockIdx.x & (CHUNKS - 1);
    const int t = threadIdx.x;

    // --- stage 1: project 64 points (threads 0..63) ---
    if (t < P_CHUNK) {
        const int p = b * PTS_PER_BATCH + c * P_CHUNK + t;
        const float x = pts[p * 3 + 0];
        const float y = pts[p * 3 + 1];
        float z = fmaxf(pts[p * 3 + 2], 0.001f);
        const float val = (z > 0.2f && z < 10.0f) ? 1.0f : 0.0f;
        const float inv = __frcp_rn(z);
        su[t] = 60.0f * x * inv + 47.5f;    // cx = (96-1)/2
        sv[t] = 60.0f * y * inv + 47.5f;
        sval[t] = val;
    }
    __syncthreads();

    // --- stage 2: fill separable exp tables (64*96*2 = 12288 exps / 256 thr = 48 each) ---
    const float kcoef = -1.0f / (2.0f * 1.5f * 1.5f);   // -0.5/sigma^2
    for (int i = t; i < P_CHUNK * 96; i += 256) {
        const int p = i / 96;
        const int cidx = i - p * 96;
        const float fc = (float)cidx;
        const float du = fc - su[p];
        const float dv = fc - sv[p];
        sex[p][cidx] = __expf(kcoef * du * du);
        sey[p][cidx] = __expf(kcoef * dv * dv) * sval[p];
    }
    __syncthreads();

    // --- stage 3: each thread owns a 6x6 pixel tile; rank-1 accumulate over 64 points ---
    const int tw = t & 15;        // 16 tiles across W
    const int th = t >> 4;        // 16 tiles down H
    const int w0 = tw * 6;
    const int h0 = th * 6;

    float acc[6][6];
#pragma unroll
    for (int i = 0; i < 6; ++i)
#pragma unroll
        for (int j = 0; j < 6; ++j) acc[i][j] = 0.0f;

    for (int p = 0; p < P_CHUNK; ++p) {
        float ex[6], ey[6];
#pragma unroll
        for (int j = 0; j < 6; ++j) ex[j] = sex[p][w0 + j];
#pragma unroll
        for (int i = 0; i < 6; ++i) ey[i] = sey[p][h0 + i];
#pragma unroll
        for (int i = 0; i < 6; ++i)
#pragma unroll
            for (int j = 0; j < 6; ++j) acc[i][j] = fmaf(ey[i], ex[j], acc[i][j]);
    }

    // --- stage 4: accumulate into global image (device-scope atomics) ---
    float* base = img + b * (HDIM * WDIM);
#pragma unroll
    for (int i = 0; i < 6; ++i)
#pragma unroll
        for (int j = 0; j < 6; ++j)
            atomicAdd(&base[(h0 + i) * WDIM + (w0 + j)], acc[i][j]);
}

__global__ __launch_bounds__(256)
void finish_kernel(float* __restrict__ img, int n) {
    const int i = blockIdx.x * 256 + threadIdx.x;
    if (i < n) img[i] = 1.0f - __expf(-img[i]);
}

extern "C" void kernel_launch(void* const* d_in, const int* in_sizes, int n_in,
                              void* d_out, int out_size, void* d_ws, size_t ws_size,
                              hipStream_t stream) {
    const float* pts = (const float*)d_in[0];
    float* out = (float*)d_out;

    hipMemsetAsync(out, 0, (size_t)out_size * sizeof(float), stream);

    splat_kernel<<<BATCHES * CHUNKS, 256, 0, stream>>>(pts, out);

    const int n = BATCHES * HDIM * WDIM;   // 36864
    finish_kernel<<<(n + 255) / 256, 256, 0, stream>>>(out, n);
}

// Round 2
// 63.712 us; speedup vs baseline: 1.3810x; 1.3810x over previous
//
#include <hip/hip_runtime.h>
#include <hip/hip_bf16.h>

// SoftPointRenderer: B=4, K=8, N=256 points -> (B,1,96,96) image.
// Separable Gaussian splat: img[b,h,w] = sum_p ey[p,h]*ex[p,w]; out = 1-exp(-img).
//
// Two-phase, atomic-free:
//   phase 1: 128 blocks (4 batches x 32 chunks of 64 pts) each write a full
//            96x96 partial image to d_ws with plain float4 stores.
//   phase 2: 36 blocks reduce the 32 partials per batch-pixel and apply
//            1-exp(-x), float4 throughout.

#define HDIM 96
#define WDIM 96
#define PIX   (HDIM * WDIM)        // 9216
#define PTS_PER_BATCH 2048         // K*N = 8*256
#define P_CHUNK 64                 // points per block
#define CHUNKS  32                 // 2048 / 64
#define BATCHES 4

__global__ __launch_bounds__(256)
void splat_partial_kernel(const float* __restrict__ pts, float* __restrict__ ws) {
    __shared__ float sex[P_CHUNK][WDIM];   // 24 KB
    __shared__ float sey[P_CHUNK][HDIM];   // 24 KB
    __shared__ float su[P_CHUNK], sv[P_CHUNK], sval[P_CHUNK];

    const int b = blockIdx.x >> 5;          // / CHUNKS
    const int c = blockIdx.x & (CHUNKS - 1);
    const int t = threadIdx.x;

    // --- stage 1: project 64 points (threads 0..63) ---
    if (t < P_CHUNK) {
        const int p = b * PTS_PER_BATCH + c * P_CHUNK + t;
        const float x = pts[p * 3 + 0];
        const float y = pts[p * 3 + 1];
        float z = fmaxf(pts[p * 3 + 2], 0.001f);
        const float val = (z > 0.2f && z < 10.0f) ? 1.0f : 0.0f;
        const float inv = __frcp_rn(z);
        su[t] = 60.0f * x * inv + 47.5f;    // cx = (96-1)/2
        sv[t] = 60.0f * y * inv + 47.5f;
        sval[t] = val;
    }
    __syncthreads();

    // --- stage 2: separable exp tables (64*96*2 exps, coalesced LDS writes) ---
    const float kcoef = -1.0f / (2.0f * 1.5f * 1.5f);   // -0.5/sigma^2
    for (int i = t; i < P_CHUNK * 96; i += 256) {
        const int p = i / 96;
        const int cidx = i - p * 96;
        const float fc = (float)cidx;
        const float du = fc - su[p];
        const float dv = fc - sv[p];
        sex[p][cidx] = __expf(kcoef * du * du);
        sey[p][cidx] = __expf(kcoef * dv * dv) * sval[p];
    }
    __syncthreads();

    // --- stage 3: each thread owns a 12-wide x 3-tall pixel tile ---
    // tw in [0,8) -> w0 = tw*12 (16B-aligned => ds_read_b128 x3)
    // th in [0,32) -> h0 = th*3
    const int tw = t & 7;
    const int th = t >> 3;
    const int w0 = tw * 12;
    const int h0 = th * 3;

    float acc[3][12];
#pragma unroll
    for (int i = 0; i < 3; ++i)
#pragma unroll
        for (int j = 0; j < 12; ++j) acc[i][j] = 0.0f;

    for (int p = 0; p < P_CHUNK; ++p) {
        const float4* exv = (const float4*)&sex[p][w0];
        float4 e0 = exv[0], e1 = exv[1], e2 = exv[2];
        float ex[12] = { e0.x, e0.y, e0.z, e0.w, e1.x, e1.y, e1.z, e1.w,
                         e2.x, e2.y, e2.z, e2.w };
        float ey[3];
#pragma unroll
        for (int i = 0; i < 3; ++i) ey[i] = sey[p][h0 + i];
#pragma unroll
        for (int i = 0; i < 3; ++i)
#pragma unroll
            for (int j = 0; j < 12; ++j) acc[i][j] = fmaf(ey[i], ex[j], acc[i][j]);
    }

    // --- stage 4: plain float4 stores of the partial image (no atomics) ---
    float* base = ws + (size_t)blockIdx.x * PIX;
#pragma unroll
    for (int i = 0; i < 3; ++i) {
        float4* dst = (float4*)&base[(h0 + i) * WDIM + w0];
#pragma unroll
        for (int q = 0; q < 3; ++q)
            dst[q] = make_float4(acc[i][4*q+0], acc[i][4*q+1], acc[i][4*q+2], acc[i][4*q+3]);
    }
}

__global__ __launch_bounds__(256)
void reduce_finish_kernel(const float* __restrict__ ws, float* __restrict__ out) {
    // one float4 (4 pixels) per thread; 4*9216/4 = 9216 threads = 36 blocks
    const int g = blockIdx.x * 256 + threadIdx.x;      // float4 index
    const int b = g / (PIX / 4);                       // batch
    const int p4 = g - b * (PIX / 4);                  // float4 index within image

    const float4* w4 = (const float4*)ws;
    float4 s = make_float4(0.f, 0.f, 0.f, 0.f);
#pragma unroll
    for (int c = 0; c < CHUNKS; ++c) {
        const float4 v = w4[(size_t)(b * CHUNKS + c) * (PIX / 4) + p4];
        s.x += v.x; s.y += v.y; s.z += v.z; s.w += v.w;
    }
    float4 r;
    r.x = 1.0f - __expf(-s.x);
    r.y = 1.0f - __expf(-s.y);
    r.z = 1.0f - __expf(-s.z);
    r.w = 1.0f - __expf(-s.w);
    ((float4*)out)[g] = r;
}

extern "C" void kernel_launch(void* const* d_in, const int* in_sizes, int n_in,
                              void* d_out, int out_size, void* d_ws, size_t ws_size,
                              hipStream_t stream) {
    const float* pts = (const float*)d_in[0];
    float* ws  = (float*)d_ws;
    float* out = (float*)d_out;

    splat_partial_kernel<<<BATCHES * CHUNKS, 256, 0, stream>>>(pts, ws);
    reduce_finish_kernel<<<(BATCHES * PIX / 4) / 256, 256, 0, stream>>>(ws, out);
}